// Round 1
// baseline (9838.651 us; speedup 1.0000x reference)
//
#include <hip/hip_runtime.h>
#include <math.h>

#define NB 4
#define NH 16
#define TT 2048
#define CC 1024
#define DD 64
#define HEAD_ELEMS ((size_t)NB * NH * TT * DD)   // 8,388,608 elements (32 MiB fp32)

// ---------------------------------------------------------------------------
// GEMM: out = A[M,K] @ B[K,N] + bias[N]
// mode 0: plain row-major Cout[m*N+n]
// mode 1: scatter qkv -> Q/K/V laid out [B,H,T,D]:
//         n -> (which = n/1024, h = (n%1024)/64, d = n%64); m -> (b = m/T, t = m%T)
// ---------------------------------------------------------------------------
__global__ __launch_bounds__(256) void gemm_kernel(
    const float* __restrict__ A, const float* __restrict__ Bm,
    const float* __restrict__ bias, float* __restrict__ Cout,
    int M, int N, int K, int mode)
{
    __shared__ float As[16][64];   // As[k][m]
    __shared__ float Bs[16][64];   // Bs[k][n]
    const int bm = blockIdx.y * 64;
    const int bn = blockIdx.x * 64;
    const int tid = threadIdx.x;
    const int tm = (tid >> 4) * 4;
    const int tn = (tid & 15) * 4;
    float acc[4][4] = {};

    for (int k0 = 0; k0 < K; k0 += 16) {
        {   // A tile: 64 rows x 16 k, transposed into As[k][m]
            int idx = tid * 4;
            int m = idx >> 4;
            int k = idx & 15;
            float4 av = *(const float4*)&A[(size_t)(bm + m) * K + k0 + k];
            As[k + 0][m] = av.x; As[k + 1][m] = av.y;
            As[k + 2][m] = av.z; As[k + 3][m] = av.w;
        }
        {   // B tile: 16 k x 64 n
            int idx = tid * 4;
            int k = idx >> 6;
            int n = idx & 63;
            *(float4*)&Bs[k][n] = *(const float4*)&Bm[(size_t)(k0 + k) * N + bn + n];
        }
        __syncthreads();
        #pragma unroll
        for (int k = 0; k < 16; k++) {
            float4 a4 = *(const float4*)&As[k][tm];
            float4 b4 = *(const float4*)&Bs[k][tn];
            float a[4] = {a4.x, a4.y, a4.z, a4.w};
            float b[4] = {b4.x, b4.y, b4.z, b4.w};
            #pragma unroll
            for (int i = 0; i < 4; i++)
                #pragma unroll
                for (int j = 0; j < 4; j++)
                    acc[i][j] = fmaf(a[i], b[j], acc[i][j]);
        }
        __syncthreads();
    }

    if (mode == 0) {
        #pragma unroll
        for (int i = 0; i < 4; i++) {
            int m = bm + tm + i;
            #pragma unroll
            for (int j = 0; j < 4; j++) {
                int n = bn + tn + j;
                Cout[(size_t)m * N + n] = acc[i][j] + bias[n];
            }
        }
    } else {
        #pragma unroll
        for (int i = 0; i < 4; i++) {
            int m = bm + tm + i;
            int b = m >> 11;       // / 2048
            int t = m & 2047;
            #pragma unroll
            for (int j = 0; j < 4; j++) {
                int n = bn + tn + j;
                int which = n >> 10;
                int c = n & 1023;
                int h = c >> 6;
                int d = c & 63;
                size_t dst = (size_t)which * HEAD_ELEMS +
                             ((((size_t)b * NH + h) * TT) + t) * DD + d;
                Cout[dst] = acc[i][j] + bias[n];
            }
        }
    }
}

// ---------------------------------------------------------------------------
// Sparsemax over D=64, one wave per vector, sort-free.
// For each element: c_i = #{z_j >= z_i}, s_i = sum{z_j : z_j >= z_i}.
// Support condition (1 + c_i*z_i > s_i) == reference's sorted-prefix condition.
// rho = sum(cond), S = sum(z*cond), tau = (S-1)/rho, out = max(z - tau, 0).
// ---------------------------------------------------------------------------
__global__ __launch_bounds__(256) void sparsemax_kernel(float* __restrict__ Kt)
{
    int wave = blockIdx.x * 4 + (threadIdx.x >> 6);
    int lane = threadIdx.x & 63;
    float* p = Kt + (size_t)wave * 64;
    float z = p[lane];

    float c = 0.f, ssum = 0.f;
    #pragma unroll
    for (int j = 0; j < 64; j++) {
        float zj = __shfl(z, j, 64);
        if (zj >= z) { c += 1.f; ssum += zj; }
    }
    float cond = (1.f + c * z > ssum) ? 1.f : 0.f;
    float rho = cond;
    float S = cond * z;
    #pragma unroll
    for (int off = 32; off; off >>= 1) {
        rho += __shfl_xor(rho, off, 64);
        S   += __shfl_xor(S,   off, 64);
    }
    float tau = (S - 1.f) / rho;
    p[lane] = fmaxf(z - tau, 0.f);
}

// ---------------------------------------------------------------------------
// Flash-style causal attention + XSA correction.
// One wave (64 lanes = D) per (b,h,q) row. Online softmax over keys 0..q.
// Epilogue: y -= (y . vhat) vhat with vhat = v[b,h,q,:]/||v||.
// Writes Y in [B,T,H,D] layout (row-major [8192,1024]) for the out-proj GEMM.
// ---------------------------------------------------------------------------
__global__ __launch_bounds__(64) void attn_kernel(
    const float* __restrict__ Q, const float* __restrict__ Kt,
    const float* __restrict__ V, float* __restrict__ Y)
{
    const int lane = threadIdx.x;
    const int q = blockIdx.x;
    const int h = blockIdx.y;
    const int b = blockIdx.z;
    const size_t base = ((size_t)(b * NH + h) * TT) * DD;

    const float qd = Q[base + (size_t)q * DD + lane] * 0.125f;  // 1/sqrt(64)
    const float* Kp = Kt + base;
    const float* Vp = V + base;

    float m = -3.0e38f, l = 0.f, o = 0.f;
    for (int j = 0; j <= q; j++) {
        float kv = Kp[(size_t)j * DD + lane];
        float s = qd * kv;
        #pragma unroll
        for (int off = 32; off; off >>= 1) s += __shfl_xor(s, off, 64);
        float mnew = fmaxf(m, s);
        float alpha = __expf(m - mnew);
        float p = __expf(s - mnew);
        l = l * alpha + p;
        o = o * alpha + p * Vp[(size_t)j * DD + lane];
        m = mnew;
    }
    float y = o / l;

    // XSA correction
    float vq = Vp[(size_t)q * DD + lane];
    float n2 = vq * vq;
    #pragma unroll
    for (int off = 32; off; off >>= 1) n2 += __shfl_xor(n2, off, 64);
    float vn = sqrtf(n2);
    float vhat = vq / fmaxf(vn, 1e-12f);
    float coef = y * vhat;
    #pragma unroll
    for (int off = 32; off; off >>= 1) coef += __shfl_xor(coef, off, 64);
    y = y - coef * vhat;

    Y[(((size_t)b * TT + q) * NH + h) * DD + lane] = y;
}

// ---------------------------------------------------------------------------
extern "C" void kernel_launch(void* const* d_in, const int* in_sizes, int n_in,
                              void* d_out, int out_size, void* d_ws, size_t ws_size,
                              hipStream_t stream) {
    const float* x      = (const float*)d_in[0];
    const float* W_attn = (const float*)d_in[1];
    const float* b_attn = (const float*)d_in[2];
    const float* W_proj = (const float*)d_in[3];
    const float* b_proj = (const float*)d_in[4];
    float* out = (float*)d_out;

    float* Q  = (float*)d_ws;
    float* Kt = Q  + HEAD_ELEMS;
    float* V  = Kt + HEAD_ELEMS;
    float* Y  = V  + HEAD_ELEMS;

    const int M = NB * TT;       // 8192

    // 1) QKV GEMM with scatter into [B,H,T,D]
    dim3 g1(3 * CC / 64, M / 64);
    gemm_kernel<<<g1, 256, 0, stream>>>(x, W_attn, b_attn, Q, M, 3 * CC, CC, 1);

    // 2) Sparsemax over D of K (in place)
    int nvec = NB * NH * TT;     // 131072
    sparsemax_kernel<<<nvec / 4, 256, 0, stream>>>(Kt);

    // 3) Fused causal attention + XSA correction
    dim3 ga(TT, NH, NB);
    attn_kernel<<<ga, 64, 0, stream>>>(Q, Kt, V, Y);

    // 4) Output projection
    dim3 g2(CC / 64, M / 64);
    gemm_kernel<<<g2, 256, 0, stream>>>(Y, W_proj, b_proj, out, M, CC, CC, 0);
}

// Round 2
// 1995.322 us; speedup vs baseline: 4.9309x; 4.9309x over previous
//
#include <hip/hip_runtime.h>
#include <math.h>

#define NB 4
#define NH 16
#define TT 2048
#define CC 1024
#define DD 64
#define HEAD_ELEMS ((size_t)NB * NH * TT * DD)   // 8,388,608 elements (32 MiB fp32)

// ---------------------------------------------------------------------------
// GEMM: out = A[M,K] @ B[K,N] + bias[N]
// mode 0: plain row-major Cout[m*N+n]
// mode 1: scatter qkv:
//   Q -> outQ transposed [b,h,d,t], scaled by 1/sqrt(D)=0.125
//   K -> outK transposed [b,h,d,t]
//   V -> outV natural    [b,h,t,d]
// ---------------------------------------------------------------------------
__global__ __launch_bounds__(256) void gemm_kernel(
    const float* __restrict__ A, const float* __restrict__ Bm,
    const float* __restrict__ bias, float* __restrict__ Cout,
    float* __restrict__ outQ, float* __restrict__ outK, float* __restrict__ outV,
    int M, int N, int K, int mode)
{
    __shared__ float As[16][64];   // As[k][m]
    __shared__ float Bs[16][64];   // Bs[k][n]
    const int bm = blockIdx.y * 64;
    const int bn = blockIdx.x * 64;
    const int tid = threadIdx.x;
    const int tm = (tid >> 4) * 4;
    const int tn = (tid & 15) * 4;
    float acc[4][4] = {};

    for (int k0 = 0; k0 < K; k0 += 16) {
        {
            int idx = tid * 4;
            int m = idx >> 4;
            int k = idx & 15;
            float4 av = *(const float4*)&A[(size_t)(bm + m) * K + k0 + k];
            As[k + 0][m] = av.x; As[k + 1][m] = av.y;
            As[k + 2][m] = av.z; As[k + 3][m] = av.w;
        }
        {
            int idx = tid * 4;
            int k = idx >> 6;
            int n = idx & 63;
            *(float4*)&Bs[k][n] = *(const float4*)&Bm[(size_t)(k0 + k) * N + bn + n];
        }
        __syncthreads();
        #pragma unroll
        for (int k = 0; k < 16; k++) {
            float4 a4 = *(const float4*)&As[k][tm];
            float4 b4 = *(const float4*)&Bs[k][tn];
            float a[4] = {a4.x, a4.y, a4.z, a4.w};
            float b[4] = {b4.x, b4.y, b4.z, b4.w};
            #pragma unroll
            for (int i = 0; i < 4; i++)
                #pragma unroll
                for (int j = 0; j < 4; j++)
                    acc[i][j] = fmaf(a[i], b[j], acc[i][j]);
        }
        __syncthreads();
    }

    if (mode == 0) {
        #pragma unroll
        for (int i = 0; i < 4; i++) {
            int m = bm + tm + i;
            #pragma unroll
            for (int j = 0; j < 4; j++) {
                int n = bn + tn + j;
                Cout[(size_t)m * N + n] = acc[i][j] + bias[n];
            }
        }
    } else {
        const int n0 = bn + tn;
        const int which = n0 >> 10;
        const int cc = n0 & 1023;
        const int h = cc >> 6;
        const int d0 = cc & 63;
        #pragma unroll
        for (int i = 0; i < 4; i++) {
            int m = bm + tm + i;
            int b = m >> 11;
            int t = m & 2047;
            size_t bh = (size_t)b * NH + h;
            if (which == 2) {
                float4 val;
                val.x = acc[i][0] + bias[n0 + 0];
                val.y = acc[i][1] + bias[n0 + 1];
                val.z = acc[i][2] + bias[n0 + 2];
                val.w = acc[i][3] + bias[n0 + 3];
                *(float4*)&outV[(bh * TT + t) * DD + d0] = val;
            } else {
                float* dst = (which == 0) ? outQ : outK;
                const float scl = (which == 0) ? 0.125f : 1.0f;
                #pragma unroll
                for (int j = 0; j < 4; j++)
                    dst[(bh * DD + d0 + j) * TT + t] = (acc[i][j] + bias[n0 + j]) * scl;
            }
        }
    }
}

// ---------------------------------------------------------------------------
// Sparsemax over D=64, operating in-place on transposed K [b,h,d,t].
// Block = (bh, 64-t-chunk): LDS transpose -> wave-per-t sparsemax -> write back.
// Sort-free: c_i=#{z_j>=z_i}, s_i=sum{z_j>=z_i}; support = (1+c_i*z_i > s_i).
// ---------------------------------------------------------------------------
__global__ __launch_bounds__(256) void sparsemax_t_kernel(float* __restrict__ Ktg)
{
    __shared__ float Ls[64][65];
    const int tc = blockIdx.x;
    const int bh = blockIdx.y;
    float* base = Ktg + (size_t)bh * DD * TT + (size_t)tc * 64;
    const int tid = threadIdx.x;
    const int g = tid >> 4, c = tid & 15;

    #pragma unroll
    for (int u = 0; u < 4; u++) {
        int d = u * 16 + g;
        float4 v = *(const float4*)&base[(size_t)d * TT + c * 4];
        Ls[d][c * 4 + 0] = v.x; Ls[d][c * 4 + 1] = v.y;
        Ls[d][c * 4 + 2] = v.z; Ls[d][c * 4 + 3] = v.w;
    }
    __syncthreads();

    const int wave = tid >> 6, lane = tid & 63;
    for (int r = 0; r < 16; r++) {
        int t = wave * 16 + r;
        float z = Ls[lane][t];
        float cnt = 0.f, ss = 0.f;
        #pragma unroll
        for (int j2 = 0; j2 < 64; j2++) {
            float zj = __shfl(z, j2, 64);
            if (zj >= z) { cnt += 1.f; ss += zj; }
        }
        float cond = (1.f + cnt * z > ss) ? 1.f : 0.f;
        float rho = cond, S = cond * z;
        #pragma unroll
        for (int off = 32; off; off >>= 1) {
            rho += __shfl_xor(rho, off, 64);
            S   += __shfl_xor(S,   off, 64);
        }
        float tau = (S - 1.f) / rho;
        Ls[lane][t] = fmaxf(z - tau, 0.f);
    }
    __syncthreads();

    #pragma unroll
    for (int u = 0; u < 4; u++) {
        int d = u * 16 + g;
        float4 v;
        v.x = Ls[d][c * 4 + 0]; v.y = Ls[d][c * 4 + 1];
        v.z = Ls[d][c * 4 + 2]; v.w = Ls[d][c * 4 + 3];
        *(float4*)&base[(size_t)d * TT + c * 4] = v;
    }
}

// ---------------------------------------------------------------------------
// Tiled flash attention + XSA correction.
// Block = 256 threads, one (b,h, 64-query tile). 4x4 micro-tile per thread.
// Q/K in LDS d-major (pre-transposed in global), P round-trips through LDS
// (aliased with K tile). 16B-group XOR swizzle keeps LDS reads conflict-free.
// ---------------------------------------------------------------------------
__global__ __launch_bounds__(256, 3) void attn_kernel(
    const float* __restrict__ Qtg, const float* __restrict__ Ktg,
    const float* __restrict__ V, float* __restrict__ Y)
{
    __shared__ float Qs[64][68];    // [d][q]
    __shared__ float KPs[64][72];   // K tile [d][k] (swizzle ^d&3) / P [q][k] (swizzle ^(q>>2)&3)
    __shared__ float Vs[64][72];    // [k][d] (swizzle ^k&3)

    const int qt = blockIdx.x, h = blockIdx.y, b = blockIdx.z;
    const size_t bh = (size_t)b * NH + h;
    const float* Qg = Qtg + bh * DD * TT;   // [d][t]
    const float* Kg = Ktg + bh * DD * TT;   // [d][t]
    const float* Vg = V + bh * TT * DD;     // [t][d]

    const int tid = threadIdx.x;
    const int g = tid >> 4, c = tid & 15;
    const int tm = g * 4, tn = c * 4;

    // stage Q tile (once): Qs[d][q] = Q[d][qt*64+q] (already scaled by 0.125)
    #pragma unroll
    for (int u = 0; u < 4; u++) {
        int d = u * 16 + g;
        float4 v = *(const float4*)&Qg[(size_t)d * TT + qt * 64 + tn];
        Qs[d][tn + 0] = v.x; Qs[d][tn + 1] = v.y;
        Qs[d][tn + 2] = v.z; Qs[d][tn + 3] = v.w;
    }

    float acc[4][4] = {};
    float m_i[4], l_i[4];
    #pragma unroll
    for (int i = 0; i < 4; i++) { m_i[i] = -3.0e38f; l_i[i] = 0.f; }

    for (int kt = 0; kt <= qt; kt++) {
        __syncthreads();   // prev O-GEMM done reading KPs(P) & Vs (also fences Q stage)
        // stage K tile: KPs[d][k] with group swizzle ^(d&3)
        #pragma unroll
        for (int u = 0; u < 4; u++) {
            int d = u * 16 + g;
            float4 v = *(const float4*)&Kg[(size_t)d * TT + kt * 64 + tn];
            *(float4*)&KPs[d][4 * (c ^ (d & 3))] = v;
        }
        // stage V tile: Vs[k][d] with group swizzle ^(k&3)
        #pragma unroll
        for (int u = 0; u < 4; u++) {
            int k = u * 16 + g;
            float4 v = *(const float4*)&Vg[(size_t)(kt * 64 + k) * DD + tn];
            *(float4*)&Vs[k][4 * (c ^ (k & 3))] = v;
        }
        __syncthreads();

        // S = Q.K^T  (s[i][j]: q=tm+i, k=tn+j)
        float s[4][4] = {};
        #pragma unroll 8
        for (int d = 0; d < 64; d++) {
            float4 qv = *(const float4*)&Qs[d][tm];
            float4 kv = *(const float4*)&KPs[d][4 * (c ^ (d & 3))];
            float a[4] = {qv.x, qv.y, qv.z, qv.w};
            float bb[4] = {kv.x, kv.y, kv.z, kv.w};
            #pragma unroll
            for (int i = 0; i < 4; i++)
                #pragma unroll
                for (int j = 0; j < 4; j++)
                    s[i][j] = fmaf(a[i], bb[j], s[i][j]);
        }

        // causal mask on diagonal tile
        if (kt == qt) {
            #pragma unroll
            for (int i = 0; i < 4; i++)
                #pragma unroll
                for (int j = 0; j < 4; j++)
                    if (tn + j > tm + i) s[i][j] = -1.0e30f;
        }

        // online softmax (rows replicated across the 16-lane c-group)
        float alpha[4];
        #pragma unroll
        for (int i = 0; i < 4; i++) {
            float rmax = fmaxf(fmaxf(s[i][0], s[i][1]), fmaxf(s[i][2], s[i][3]));
            #pragma unroll
            for (int off = 8; off; off >>= 1)
                rmax = fmaxf(rmax, __shfl_xor(rmax, off, 64));
            float mnew = fmaxf(m_i[i], rmax);
            alpha[i] = __expf(m_i[i] - mnew);
            float rs = 0.f;
            #pragma unroll
            for (int j = 0; j < 4; j++) {
                float p = __expf(s[i][j] - mnew);
                s[i][j] = p;
                rs += p;
            }
            #pragma unroll
            for (int off = 8; off; off >>= 1)
                rs += __shfl_xor(rs, off, 64);
            l_i[i] = l_i[i] * alpha[i] + rs;
            m_i[i] = mnew;
        }
        #pragma unroll
        for (int i = 0; i < 4; i++)
            #pragma unroll
            for (int j = 0; j < 4; j++)
                acc[i][j] *= alpha[i];

        __syncthreads();   // all S-GEMM reads of KPs done before P overwrite
        // write P: rows q=tm+i, cols tn.., group swizzle ^(g&3) ((q>>2)&3 == g&3)
        #pragma unroll
        for (int i = 0; i < 4; i++) {
            float4 pv = {s[i][0], s[i][1], s[i][2], s[i][3]};
            *(float4*)&KPs[tm + i][4 * (c ^ (g & 3))] = pv;
        }
        __syncthreads();

        // O += P.V  (acc[i][j]: q=tm+i, d=tn+j)
        #pragma unroll 4
        for (int k0 = 0; k0 < 64; k0 += 4) {
            float4 pv[4], vv[4];
            #pragma unroll
            for (int i = 0; i < 4; i++)
                pv[i] = *(const float4*)&KPs[tm + i][4 * ((k0 >> 2) ^ (g & 3))];
            #pragma unroll
            for (int kk = 0; kk < 4; kk++)
                vv[kk] = *(const float4*)&Vs[k0 + kk][4 * (c ^ ((k0 + kk) & 3))];
            #pragma unroll
            for (int i = 0; i < 4; i++) {
                float pr[4] = {pv[i].x, pv[i].y, pv[i].z, pv[i].w};
                #pragma unroll
                for (int kk = 0; kk < 4; kk++) {
                    float vr[4] = {vv[kk].x, vv[kk].y, vv[kk].z, vv[kk].w};
                    #pragma unroll
                    for (int j = 0; j < 4; j++)
                        acc[i][j] = fmaf(pr[kk], vr[j], acc[i][j]);
                }
            }
        }
    }

    // epilogue: normalize, XSA correction, store Y in [B,T,H,D]
    #pragma unroll
    for (int i = 0; i < 4; i++) {
        const int q = qt * 64 + tm + i;
        const float inv_l = 1.0f / l_i[i];
        float y[4];
        #pragma unroll
        for (int j = 0; j < 4; j++) y[j] = acc[i][j] * inv_l;

        float4 vq4 = *(const float4*)&Vg[(size_t)q * DD + tn];
        float vq[4] = {vq4.x, vq4.y, vq4.z, vq4.w};
        float n2 = vq[0]*vq[0] + vq[1]*vq[1] + vq[2]*vq[2] + vq[3]*vq[3];
        #pragma unroll
        for (int off = 8; off; off >>= 1) n2 += __shfl_xor(n2, off, 64);
        float inv_vn = 1.0f / fmaxf(sqrtf(n2), 1e-12f);

        float coef = 0.f;
        #pragma unroll
        for (int j = 0; j < 4; j++) coef += y[j] * (vq[j] * inv_vn);
        #pragma unroll
        for (int off = 8; off; off >>= 1) coef += __shfl_xor(coef, off, 64);

        float4 out;
        out.x = y[0] - coef * vq[0] * inv_vn;
        out.y = y[1] - coef * vq[1] * inv_vn;
        out.z = y[2] - coef * vq[2] * inv_vn;
        out.w = y[3] - coef * vq[3] * inv_vn;
        *(float4*)&Y[(((size_t)b * TT + q) * NH + h) * DD + tn] = out;
    }
}

// ---------------------------------------------------------------------------
extern "C" void kernel_launch(void* const* d_in, const int* in_sizes, int n_in,
                              void* d_out, int out_size, void* d_ws, size_t ws_size,
                              hipStream_t stream) {
    const float* x      = (const float*)d_in[0];
    const float* W_attn = (const float*)d_in[1];
    const float* b_attn = (const float*)d_in[2];
    const float* W_proj = (const float*)d_in[3];
    const float* b_proj = (const float*)d_in[4];
    float* out = (float*)d_out;

    float* Qtg = (float*)d_ws;          // [B,H,D,T] (pre-scaled)
    float* Ktg = Qtg + HEAD_ELEMS;      // [B,H,D,T]
    float* V   = Ktg + HEAD_ELEMS;      // [B,H,T,D]
    float* Y   = V   + HEAD_ELEMS;      // [B,T,H*D]

    const int M = NB * TT;              // 8192

    dim3 g1(3 * CC / 64, M / 64);
    gemm_kernel<<<g1, 256, 0, stream>>>(x, W_attn, b_attn, nullptr,
                                        Qtg, Ktg, V, M, 3 * CC, CC, 1);

    dim3 gs(TT / 64, NB * NH);
    sparsemax_t_kernel<<<gs, 256, 0, stream>>>(Ktg);

    dim3 ga(TT / 64, NH, NB);
    attn_kernel<<<ga, 256, 0, stream>>>(Qtg, Ktg, V, Y);

    dim3 g2(CC / 64, M / 64);
    gemm_kernel<<<g2, 256, 0, stream>>>(Y, W_proj, b_proj, out,
                                        nullptr, nullptr, nullptr, M, CC, CC, 0);
}

// Round 3
// 1738.019 us; speedup vs baseline: 5.6608x; 1.1480x over previous
//
#include <hip/hip_runtime.h>
#include <math.h>

#define NB 4
#define NH 16
#define TT 2048
#define CC 1024
#define DD 64
#define HEAD_ELEMS ((size_t)NB * NH * TT * DD)   // 8,388,608 elements (32 MiB fp32)

// ---------------------------------------------------------------------------
// GEMM: out = A[M,K] @ B[K,N] + bias[N]. 128x128 tile, BK=8, 8x8 micro-tile,
// double-buffered LDS (one barrier/iter), register-prefetched staging.
// mode 0: plain row-major Cout[m*N+n]
// mode 1: scatter qkv:
//   Q -> outQ transposed [b,h,d,t], scaled by 1/sqrt(D)=0.125
//   K -> outK transposed [b,h,d,t]
//   V -> outV natural    [b,h,t,d]
// ---------------------------------------------------------------------------
__global__ __launch_bounds__(256) void gemm_kernel(
    const float* __restrict__ A, const float* __restrict__ Bm,
    const float* __restrict__ bias, float* __restrict__ Cout,
    float* __restrict__ outQ, float* __restrict__ outK, float* __restrict__ outV,
    int M, int N, int K, int mode)
{
    __shared__ float As[2][8][132];   // As[buf][k][m]
    __shared__ float Bs[2][8][132];   // Bs[buf][k][n]
    const int bm = blockIdx.y * 128;
    const int bn = blockIdx.x * 128;
    const int tid = threadIdx.x;
    const int tx = tid & 15, ty = tid >> 4;
    const int ar = tid >> 1, ak = (tid & 1) * 4;    // A stage: row, k-offset
    const int bkr = tid >> 5, bc = (tid & 31) * 4;  // B stage: k-row, col

    const float* Aptr = A + (size_t)(bm + ar) * K + ak;
    const float* Bptr = Bm + (size_t)bkr * N + bn + bc;

    float acc[8][8] = {};

    // prologue: tile0 -> buf0, prefetch tile1 into regs
    float4 av = *(const float4*)Aptr;
    float4 bv = *(const float4*)Bptr;
    As[0][ak + 0][ar] = av.x; As[0][ak + 1][ar] = av.y;
    As[0][ak + 2][ar] = av.z; As[0][ak + 3][ar] = av.w;
    *(float4*)&Bs[0][bkr][bc] = bv;
    av = *(const float4*)(Aptr + 8);
    bv = *(const float4*)(Bptr + (size_t)8 * N);
    __syncthreads();

    int buf = 0;
    for (int k0 = 0; k0 < K; k0 += 8) {
        if (k0 + 8 < K) {
            const int nb = buf ^ 1;
            As[nb][ak + 0][ar] = av.x; As[nb][ak + 1][ar] = av.y;
            As[nb][ak + 2][ar] = av.z; As[nb][ak + 3][ar] = av.w;
            *(float4*)&Bs[nb][bkr][bc] = bv;
            if (k0 + 16 < K) {
                av = *(const float4*)(Aptr + k0 + 16);
                bv = *(const float4*)(Bptr + (size_t)(k0 + 16) * N);
            }
        }
        #pragma unroll
        for (int k = 0; k < 8; k++) {
            float4 a0 = *(const float4*)&As[buf][k][ty * 4];
            float4 a1 = *(const float4*)&As[buf][k][64 + ty * 4];
            float4 b0 = *(const float4*)&Bs[buf][k][tx * 4];
            float4 b1 = *(const float4*)&Bs[buf][k][64 + tx * 4];
            float a[8] = {a0.x, a0.y, a0.z, a0.w, a1.x, a1.y, a1.z, a1.w};
            float b[8] = {b0.x, b0.y, b0.z, b0.w, b1.x, b1.y, b1.z, b1.w};
            #pragma unroll
            for (int i = 0; i < 8; i++)
                #pragma unroll
                for (int j = 0; j < 8; j++)
                    acc[i][j] = fmaf(a[i], b[j], acc[i][j]);
        }
        buf ^= 1;
        __syncthreads();
    }

    if (mode == 0) {
        #pragma unroll
        for (int hi = 0; hi < 2; hi++)
            #pragma unroll
            for (int i = 0; i < 4; i++) {
                const int m = bm + hi * 64 + ty * 4 + i;
                #pragma unroll
                for (int hj = 0; hj < 2; hj++) {
                    const int n = bn + hj * 64 + tx * 4;
                    float4 o;
                    o.x = acc[hi * 4 + i][hj * 4 + 0] + bias[n + 0];
                    o.y = acc[hi * 4 + i][hj * 4 + 1] + bias[n + 1];
                    o.z = acc[hi * 4 + i][hj * 4 + 2] + bias[n + 2];
                    o.w = acc[hi * 4 + i][hj * 4 + 3] + bias[n + 3];
                    *(float4*)&Cout[(size_t)m * N + n] = o;
                }
            }
    } else {
        #pragma unroll
        for (int hi = 0; hi < 2; hi++)
            #pragma unroll
            for (int i = 0; i < 4; i++) {
                const int m = bm + hi * 64 + ty * 4 + i;
                const int b = m >> 11;
                const int t = m & 2047;
                #pragma unroll
                for (int hj = 0; hj < 2; hj++) {
                    const int n0 = bn + hj * 64 + tx * 4;
                    const int which = n0 >> 10;
                    const int cc_ = n0 & 1023;
                    const int h = cc_ >> 6;
                    const int d0 = cc_ & 63;
                    const size_t bh = (size_t)b * NH + h;
                    if (which == 2) {
                        float4 val;
                        val.x = acc[hi * 4 + i][hj * 4 + 0] + bias[n0 + 0];
                        val.y = acc[hi * 4 + i][hj * 4 + 1] + bias[n0 + 1];
                        val.z = acc[hi * 4 + i][hj * 4 + 2] + bias[n0 + 2];
                        val.w = acc[hi * 4 + i][hj * 4 + 3] + bias[n0 + 3];
                        *(float4*)&outV[(bh * TT + t) * DD + d0] = val;
                    } else {
                        float* dst = (which == 0) ? outQ : outK;
                        const float scl = (which == 0) ? 0.125f : 1.0f;
                        #pragma unroll
                        for (int j = 0; j < 4; j++)
                            dst[(bh * DD + d0 + j) * TT + t] =
                                (acc[hi * 4 + i][hj * 4 + j] + bias[n0 + j]) * scl;
                    }
                }
            }
    }
}

// ---------------------------------------------------------------------------
// Sparsemax over D=64, in-place on transposed K [b,h,d,t]. Sort-free.
// ---------------------------------------------------------------------------
__global__ __launch_bounds__(256) void sparsemax_t_kernel(float* __restrict__ Ktg)
{
    __shared__ float Ls[64][65];
    const int tc = blockIdx.x;
    const int bh = blockIdx.y;
    float* base = Ktg + (size_t)bh * DD * TT + (size_t)tc * 64;
    const int tid = threadIdx.x;
    const int g = tid >> 4, c = tid & 15;

    #pragma unroll
    for (int u = 0; u < 4; u++) {
        int d = u * 16 + g;
        float4 v = *(const float4*)&base[(size_t)d * TT + c * 4];
        Ls[d][c * 4 + 0] = v.x; Ls[d][c * 4 + 1] = v.y;
        Ls[d][c * 4 + 2] = v.z; Ls[d][c * 4 + 3] = v.w;
    }
    __syncthreads();

    const int wave = tid >> 6, lane = tid & 63;
    for (int r = 0; r < 16; r++) {
        int t = wave * 16 + r;
        float z = Ls[lane][t];
        float cnt = 0.f, ss = 0.f;
        #pragma unroll
        for (int j2 = 0; j2 < 64; j2++) {
            float zj = __shfl(z, j2, 64);
            if (zj >= z) { cnt += 1.f; ss += zj; }
        }
        float cond = (1.f + cnt * z > ss) ? 1.f : 0.f;
        float rho = cond, S = cond * z;
        #pragma unroll
        for (int off = 32; off; off >>= 1) {
            rho += __shfl_xor(rho, off, 64);
            S   += __shfl_xor(S,   off, 64);
        }
        float tau = (S - 1.f) / rho;
        Ls[lane][t] = fmaxf(z - tau, 0.f);
    }
    __syncthreads();

    #pragma unroll
    for (int u = 0; u < 4; u++) {
        int d = u * 16 + g;
        float4 v;
        v.x = Ls[d][c * 4 + 0]; v.y = Ls[d][c * 4 + 1];
        v.z = Ls[d][c * 4 + 2]; v.w = Ls[d][c * 4 + 3];
        *(float4*)&base[(size_t)d * TT + c * 4] = v;
    }
}

// ---------------------------------------------------------------------------
// Tiled flash attention + XSA correction.
// 512 blocks, each handles 4 q-tiles {p, 31-p, p+8, 23-p} -> uniform 66 tiles
// of work per block (no tail imbalance). K/V staged via register prefetch so
// global latency hides behind the S/P/O compute of the previous tile.
// ---------------------------------------------------------------------------
__global__ __launch_bounds__(256, 3) void attn_kernel(
    const float* __restrict__ Qtg, const float* __restrict__ Ktg,
    const float* __restrict__ V, float* __restrict__ Y)
{
    __shared__ float Qs[64][68];    // [d][q]
    __shared__ float KPs[64][72];   // K tile [d][k] (^d&3) / P [q][k] (^(q>>2)&3)
    __shared__ float Vs[64][72];    // [k][d] (^k&3)

    const int blk = blockIdx.x;         // 0..511
    const int bhid = blk >> 3;          // 0..63
    const int p = blk & 7;              // 0..7
    const int b = bhid >> 4, h = bhid & 15;
    const size_t bh = (size_t)b * NH + h;
    const float* Qg = Qtg + bh * DD * TT;   // [d][t]
    const float* Kg = Ktg + bh * DD * TT;   // [d][t]
    const float* Vg = V + bh * TT * DD;     // [t][d]

    const int tid = threadIdx.x;
    const int g = tid >> 4, c = tid & 15;
    const int tm = g * 4, tn = c * 4;

    const int qlist[4] = {p, 31 - p, p + 8, 23 - p};

    for (int qi = 0; qi < 4; qi++) {
        const int qt = qlist[qi];
        __syncthreads();   // prior q-tile fully done (Qs/KPs/Vs reads)

        // stage Q tile: Qs[d][q] (already scaled by 0.125)
        #pragma unroll
        for (int u = 0; u < 4; u++) {
            int d = u * 16 + g;
            float4 v = *(const float4*)&Qg[(size_t)d * TT + qt * 64 + tn];
            Qs[d][tn + 0] = v.x; Qs[d][tn + 1] = v.y;
            Qs[d][tn + 2] = v.z; Qs[d][tn + 3] = v.w;
        }

        // prefetch kt=0 K/V into registers
        float4 kpre[4], vpre[4];
        #pragma unroll
        for (int u = 0; u < 4; u++) {
            int d = u * 16 + g;
            kpre[u] = *(const float4*)&Kg[(size_t)d * TT + tn];
            vpre[u] = *(const float4*)&Vg[(size_t)(u * 16 + g) * DD + tn];
        }

        float acc[4][4] = {};
        float m_i[4], l_i[4];
        #pragma unroll
        for (int i = 0; i < 4; i++) { m_i[i] = -3.0e38f; l_i[i] = 0.f; }

        for (int kt = 0; kt <= qt; kt++) {
            __syncthreads();   // prev O-GEMM reads of KPs/Vs done; Qs staged (kt=0)
            // commit prefetched K/V to LDS
            #pragma unroll
            for (int u = 0; u < 4; u++) {
                int d = u * 16 + g;
                *(float4*)&KPs[d][4 * (c ^ (d & 3))] = kpre[u];
                *(float4*)&Vs[d][4 * (c ^ (d & 3))] = vpre[u];
            }
            // issue next tile's loads (consumed after next barrier -> hidden)
            if (kt < qt) {
                const int kn = (kt + 1) * 64;
                #pragma unroll
                for (int u = 0; u < 4; u++) {
                    int d = u * 16 + g;
                    kpre[u] = *(const float4*)&Kg[(size_t)d * TT + kn + tn];
                    vpre[u] = *(const float4*)&Vg[(size_t)(kn + u * 16 + g) * DD + tn];
                }
            }
            __syncthreads();

            // S = Q.K^T  (s[i][j]: q=tm+i, k=tn+j)
            float s[4][4] = {};
            #pragma unroll 8
            for (int d = 0; d < 64; d++) {
                float4 qv = *(const float4*)&Qs[d][tm];
                float4 kv = *(const float4*)&KPs[d][4 * (c ^ (d & 3))];
                float a[4] = {qv.x, qv.y, qv.z, qv.w};
                float bb[4] = {kv.x, kv.y, kv.z, kv.w};
                #pragma unroll
                for (int i = 0; i < 4; i++)
                    #pragma unroll
                    for (int j = 0; j < 4; j++)
                        s[i][j] = fmaf(a[i], bb[j], s[i][j]);
            }

            if (kt == qt) {
                #pragma unroll
                for (int i = 0; i < 4; i++)
                    #pragma unroll
                    for (int j = 0; j < 4; j++)
                        if (tn + j > tm + i) s[i][j] = -1.0e30f;
            }

            // online softmax (rows replicated across the 16-lane c-group)
            float alpha[4];
            #pragma unroll
            for (int i = 0; i < 4; i++) {
                float rmax = fmaxf(fmaxf(s[i][0], s[i][1]), fmaxf(s[i][2], s[i][3]));
                #pragma unroll
                for (int off = 8; off; off >>= 1)
                    rmax = fmaxf(rmax, __shfl_xor(rmax, off, 64));
                float mnew = fmaxf(m_i[i], rmax);
                alpha[i] = __expf(m_i[i] - mnew);
                float rs = 0.f;
                #pragma unroll
                for (int j = 0; j < 4; j++) {
                    float pp = __expf(s[i][j] - mnew);
                    s[i][j] = pp;
                    rs += pp;
                }
                #pragma unroll
                for (int off = 8; off; off >>= 1)
                    rs += __shfl_xor(rs, off, 64);
                l_i[i] = l_i[i] * alpha[i] + rs;
                m_i[i] = mnew;
            }
            #pragma unroll
            for (int i = 0; i < 4; i++)
                #pragma unroll
                for (int j = 0; j < 4; j++)
                    acc[i][j] *= alpha[i];

            __syncthreads();   // all S-GEMM reads of KPs done before P overwrite
            #pragma unroll
            for (int i = 0; i < 4; i++) {
                float4 pv = {s[i][0], s[i][1], s[i][2], s[i][3]};
                *(float4*)&KPs[tm + i][4 * (c ^ (g & 3))] = pv;
            }
            __syncthreads();

            // O += P.V  (acc[i][j]: q=tm+i, d=tn+j)
            #pragma unroll 4
            for (int k0 = 0; k0 < 64; k0 += 4) {
                float4 pv[4], vv[4];
                #pragma unroll
                for (int i = 0; i < 4; i++)
                    pv[i] = *(const float4*)&KPs[tm + i][4 * ((k0 >> 2) ^ (g & 3))];
                #pragma unroll
                for (int kk = 0; kk < 4; kk++)
                    vv[kk] = *(const float4*)&Vs[k0 + kk][4 * (c ^ ((k0 + kk) & 3))];
                #pragma unroll
                for (int i = 0; i < 4; i++) {
                    float pr[4] = {pv[i].x, pv[i].y, pv[i].z, pv[i].w};
                    #pragma unroll
                    for (int kk = 0; kk < 4; kk++) {
                        float vr[4] = {vv[kk].x, vv[kk].y, vv[kk].z, vv[kk].w};
                        #pragma unroll
                        for (int j = 0; j < 4; j++)
                            acc[i][j] = fmaf(pr[kk], vr[j], acc[i][j]);
                    }
                }
            }
        }

        // epilogue: normalize, XSA correction, store Y in [B,T,H,D]
        #pragma unroll
        for (int i = 0; i < 4; i++) {
            const int q = qt * 64 + tm + i;
            const float inv_l = 1.0f / l_i[i];
            float y[4];
            #pragma unroll
            for (int j = 0; j < 4; j++) y[j] = acc[i][j] * inv_l;

            float4 vq4 = *(const float4*)&Vg[(size_t)q * DD + tn];
            float vq[4] = {vq4.x, vq4.y, vq4.z, vq4.w};
            float n2 = vq[0]*vq[0] + vq[1]*vq[1] + vq[2]*vq[2] + vq[3]*vq[3];
            #pragma unroll
            for (int off = 8; off; off >>= 1) n2 += __shfl_xor(n2, off, 64);
            float inv_vn = 1.0f / fmaxf(sqrtf(n2), 1e-12f);

            float coef = 0.f;
            #pragma unroll
            for (int j = 0; j < 4; j++) coef += y[j] * (vq[j] * inv_vn);
            #pragma unroll
            for (int off = 8; off; off >>= 1) coef += __shfl_xor(coef, off, 64);

            float4 o;
            o.x = y[0] - coef * vq[0] * inv_vn;
            o.y = y[1] - coef * vq[1] * inv_vn;
            o.z = y[2] - coef * vq[2] * inv_vn;
            o.w = y[3] - coef * vq[3] * inv_vn;
            *(float4*)&Y[(((size_t)b * TT + q) * NH + h) * DD + tn] = o;
        }
    }
}

// ---------------------------------------------------------------------------
extern "C" void kernel_launch(void* const* d_in, const int* in_sizes, int n_in,
                              void* d_out, int out_size, void* d_ws, size_t ws_size,
                              hipStream_t stream) {
    const float* x      = (const float*)d_in[0];
    const float* W_attn = (const float*)d_in[1];
    const float* b_attn = (const float*)d_in[2];
    const float* W_proj = (const float*)d_in[3];
    const float* b_proj = (const float*)d_in[4];
    float* out = (float*)d_out;

    float* Qtg = (float*)d_ws;          // [B,H,D,T] (pre-scaled)
    float* Ktg = Qtg + HEAD_ELEMS;      // [B,H,D,T]
    float* V   = Ktg + HEAD_ELEMS;      // [B,H,T,D]
    float* Y   = V   + HEAD_ELEMS;      // [B,T,H*D]

    const int M = NB * TT;              // 8192

    dim3 g1(3 * CC / 128, M / 128);
    gemm_kernel<<<g1, 256, 0, stream>>>(x, W_attn, b_attn, nullptr,
                                        Qtg, Ktg, V, M, 3 * CC, CC, 1);

    dim3 gs(TT / 64, NB * NH);
    sparsemax_t_kernel<<<gs, 256, 0, stream>>>(Ktg);

    attn_kernel<<<dim3(512), 256, 0, stream>>>(Qtg, Ktg, V, Y);

    dim3 g2(CC / 128, M / 128);
    gemm_kernel<<<g2, 256, 0, stream>>>(Y, W_proj, b_proj, out,
                                        nullptr, nullptr, nullptr, M, CC, CC, 0);
}

// Round 7
// 1082.291 us; speedup vs baseline: 9.0906x; 1.6059x over previous
//
#include <hip/hip_runtime.h>
#include <math.h>

#define NB 4
#define NH 16
#define TT 2048
#define CC 1024
#define DD 64
#define MM (NB * TT)   // 8192

typedef __attribute__((ext_vector_type(8))) _Float16 half8;
typedef __attribute__((ext_vector_type(4))) _Float16 half4;
typedef __attribute__((ext_vector_type(4))) float floatx4;

// ---------------------------------------------------------------------------
// Elementwise split: x fp32 -> xh + xl (fp16 pair), same [M,K] layout.
// xh = (f16)x (RNE); xl = (f16)(x - xh). Combined ~22-bit mantissa.
// ---------------------------------------------------------------------------
__global__ __launch_bounds__(256) void split_x_kernel(
    const float* __restrict__ x, _Float16* __restrict__ xh,
    _Float16* __restrict__ xl)
{
    size_t i = ((size_t)blockIdx.x * 256 + threadIdx.x) * 4;
    float4 v = *(const float4*)&x[i];
    half4 h, l;
    h.x = (_Float16)v.x; l.x = (_Float16)(v.x - (float)h.x);
    h.y = (_Float16)v.y; l.y = (_Float16)(v.y - (float)h.y);
    h.z = (_Float16)v.z; l.z = (_Float16)(v.z - (float)h.z);
    h.w = (_Float16)v.w; l.w = (_Float16)(v.w - (float)h.w);
    *(half4*)&xh[i] = h;
    *(half4*)&xl[i] = l;
}

// ---------------------------------------------------------------------------
// Transpose + split: W [K,N] fp32 -> WhT + WlT [N,K] fp16 (k-major for MFMA).
// ---------------------------------------------------------------------------
__global__ __launch_bounds__(256) void splitT_w_kernel(
    const float* __restrict__ W, _Float16* __restrict__ WhT,
    _Float16* __restrict__ WlT, int K, int N)
{
    __shared__ float Ls[64][65];
    const int bN = blockIdx.x * 64;
    const int bK = blockIdx.y * 64;
    const int tid = threadIdx.x;
    const int g = tid >> 4, c = tid & 15;

    #pragma unroll
    for (int u = 0; u < 4; u++) {
        int r = u * 16 + g;
        float4 v = *(const float4*)&W[(size_t)(bK + r) * N + bN + c * 4];
        Ls[r][c * 4 + 0] = v.x; Ls[r][c * 4 + 1] = v.y;
        Ls[r][c * 4 + 2] = v.z; Ls[r][c * 4 + 3] = v.w;
    }
    __syncthreads();
    #pragma unroll
    for (int u = 0; u < 4; u++) {
        int n = u * 16 + g;
        half4 h, l;
        float f;
        f = Ls[c * 4 + 0][n]; h.x = (_Float16)f; l.x = (_Float16)(f - (float)h.x);
        f = Ls[c * 4 + 1][n]; h.y = (_Float16)f; l.y = (_Float16)(f - (float)h.y);
        f = Ls[c * 4 + 2][n]; h.z = (_Float16)f; l.z = (_Float16)(f - (float)h.z);
        f = Ls[c * 4 + 3][n]; h.w = (_Float16)f; l.w = (_Float16)(f - (float)h.w);
        size_t o = (size_t)(bN + n) * K + bK + c * 4;
        *(half4*)&WhT[o] = h;
        *(half4*)&WlT[o] = l;
    }
}

// ---------------------------------------------------------------------------
// Split-fp16 MFMA GEMM: C[M,N] = (Ah+Al)[M,K] x (Bh+Bl)^T[N,K] + bias.
// 3-term: ah*bh + ah*bl + al*bh (al*bl dropped, ~2^-22 relative).
// 128x128 block tile, BK=32, 16x16x32 f16 MFMA, explicit-load LDS staging.
// mode 0: Cout[m*N+n] fp32 + bias
// mode 1: qkv scatter: Q -> fp32 [b,h,d,t] scaled 0.125; K -> fp32 [b,h,d,t];
//         V -> fp16 [b,h,t,d]
// ---------------------------------------------------------------------------
__global__ __launch_bounds__(256) void gemm_ht3_kernel(
    const _Float16* __restrict__ Ah, const _Float16* __restrict__ Al,
    const _Float16* __restrict__ Bh, const _Float16* __restrict__ Bl,
    const float* __restrict__ bias, float* __restrict__ Cout,
    float* __restrict__ outQ, float* __restrict__ outK,
    _Float16* __restrict__ outV, int N, int K, int mode)
{
    __shared__ _Float16 sAh[128 * 32], sAl[128 * 32];
    __shared__ _Float16 sBh[128 * 32], sBl[128 * 32];   // 32 KB total

    const int bn = blockIdx.x * 128;
    const int bm = blockIdx.y * 128;
    const int tid = threadIdx.x;
    const int w = tid >> 6, lane = tid & 63;
    const int wm = (w >> 1) * 64, wn = (w & 1) * 64;

    // staging: wave w covers rows [w*32, w*32+32) of each 128x32 tile.
    // lane -> row w*32 + (lane>>2), k-offset (lane&3)*8 halfs (16 B).
    const int rowS = w * 32 + (lane >> 2);
    const int kg = (lane & 3) * 8;
    const size_t offA0 = (size_t)(bm + rowS) * K + kg;
    const size_t offA1 = offA0 + (size_t)16 * K;
    const size_t offB0 = (size_t)(bn + rowS) * K + kg;
    const size_t offB1 = offB0 + (size_t)16 * K;
    const int ls0 = rowS * 32 + kg;          // half index in LDS tile
    const int ls1 = (rowS + 16) * 32 + kg;

    floatx4 acc[4][4];
    #pragma unroll
    for (int i = 0; i < 4; i++)
        #pragma unroll
        for (int j = 0; j < 4; j++)
            acc[i][j] = (floatx4){0.f, 0.f, 0.f, 0.f};

    const int fr = lane & 15, fq = (lane >> 4) * 8;

    for (int k0 = 0; k0 < K; k0 += 32) {
        __syncthreads();   // prev iter's frag reads done; LDS reusable
        half8 a0 = *(const half8*)&Ah[offA0 + k0];
        half8 a1 = *(const half8*)&Ah[offA1 + k0];
        half8 a2 = *(const half8*)&Al[offA0 + k0];
        half8 a3 = *(const half8*)&Al[offA1 + k0];
        half8 b0 = *(const half8*)&Bh[offB0 + k0];
        half8 b1 = *(const half8*)&Bh[offB1 + k0];
        half8 b2 = *(const half8*)&Bl[offB0 + k0];
        half8 b3 = *(const half8*)&Bl[offB1 + k0];
        *(half8*)&sAh[ls0] = a0;
        *(half8*)&sAh[ls1] = a1;
        *(half8*)&sAl[ls0] = a2;
        *(half8*)&sAl[ls1] = a3;
        *(half8*)&sBh[ls0] = b0;
        *(half8*)&sBh[ls1] = b1;
        *(half8*)&sBl[ls0] = b2;
        *(half8*)&sBl[ls1] = b3;
        __syncthreads();

        half8 ah[4], al[4], bh[4], bl[4];
        #pragma unroll
        for (int t = 0; t < 4; t++) {
            ah[t] = *(const half8*)&sAh[(wm + t * 16 + fr) * 32 + fq];
            al[t] = *(const half8*)&sAl[(wm + t * 16 + fr) * 32 + fq];
            bh[t] = *(const half8*)&sBh[(wn + t * 16 + fr) * 32 + fq];
            bl[t] = *(const half8*)&sBl[(wn + t * 16 + fr) * 32 + fq];
        }
        #pragma unroll
        for (int mt = 0; mt < 4; mt++)
            #pragma unroll
            for (int nt = 0; nt < 4; nt++) {
                acc[mt][nt] = __builtin_amdgcn_mfma_f32_16x16x32_f16(
                    ah[mt], bh[nt], acc[mt][nt], 0, 0, 0);
                acc[mt][nt] = __builtin_amdgcn_mfma_f32_16x16x32_f16(
                    ah[mt], bl[nt], acc[mt][nt], 0, 0, 0);
                acc[mt][nt] = __builtin_amdgcn_mfma_f32_16x16x32_f16(
                    al[mt], bh[nt], acc[mt][nt], 0, 0, 0);
            }
    }

    // epilogue: C/D mapping col=lane&15 (n), row=(lane>>4)*4+reg (m)
    const int col = lane & 15, row4 = (lane >> 4) * 4;
    if (mode == 0) {
        #pragma unroll
        for (int mt = 0; mt < 4; mt++)
            #pragma unroll
            for (int nt = 0; nt < 4; nt++) {
                const int n = bn + wn + nt * 16 + col;
                const float bv = bias[n];
                const int m0 = bm + wm + mt * 16 + row4;
                #pragma unroll
                for (int r = 0; r < 4; r++)
                    Cout[(size_t)(m0 + r) * N + n] = acc[mt][nt][r] + bv;
            }
    } else {
        #pragma unroll
        for (int mt = 0; mt < 4; mt++)
            #pragma unroll
            for (int nt = 0; nt < 4; nt++) {
                const int n = bn + wn + nt * 16 + col;
                const int which = n >> 10;
                const int cc_ = n & 1023;
                const int h = cc_ >> 6, d = cc_ & 63;
                const int m0 = bm + wm + mt * 16 + row4;
                const int b = m0 >> 11, t0 = m0 & 2047;
                const size_t bh_ = (size_t)b * NH + h;
                const float bv = bias[n];
                if (which == 0) {        // Q: fp32 [b,h,d,t], pre-scaled
                    float4 qv;
                    qv.x = (acc[mt][nt][0] + bv) * 0.125f;
                    qv.y = (acc[mt][nt][1] + bv) * 0.125f;
                    qv.z = (acc[mt][nt][2] + bv) * 0.125f;
                    qv.w = (acc[mt][nt][3] + bv) * 0.125f;
                    *(float4*)&outQ[(bh_ * DD + d) * TT + t0] = qv;
                } else if (which == 1) { // K: fp32 [b,h,d,t]
                    float4 kv;
                    kv.x = acc[mt][nt][0] + bv;
                    kv.y = acc[mt][nt][1] + bv;
                    kv.z = acc[mt][nt][2] + bv;
                    kv.w = acc[mt][nt][3] + bv;
                    *(float4*)&outK[(bh_ * DD + d) * TT + t0] = kv;
                } else {                 // V: fp16 [b,h,t,d]
                    #pragma unroll
                    for (int r = 0; r < 4; r++)
                        outV[(bh_ * TT + t0 + r) * DD + d] =
                            (_Float16)(acc[mt][nt][r] + bv);
                }
            }
    }
}

// ---------------------------------------------------------------------------
// Sparsemax over D=64, in-place on transposed K [b,h,d,t]. Sort-free.
// ---------------------------------------------------------------------------
__global__ __launch_bounds__(256) void sparsemax_t_kernel(float* __restrict__ Ktg)
{
    __shared__ float Ls[64][65];
    const int tc = blockIdx.x;
    const int bh = blockIdx.y;
    float* base = Ktg + (size_t)bh * DD * TT + (size_t)tc * 64;
    const int tid = threadIdx.x;
    const int g = tid >> 4, c = tid & 15;

    #pragma unroll
    for (int u = 0; u < 4; u++) {
        int d = u * 16 + g;
        float4 v = *(const float4*)&base[(size_t)d * TT + c * 4];
        Ls[d][c * 4 + 0] = v.x; Ls[d][c * 4 + 1] = v.y;
        Ls[d][c * 4 + 2] = v.z; Ls[d][c * 4 + 3] = v.w;
    }
    __syncthreads();

    const int wave = tid >> 6, lane = tid & 63;
    for (int r = 0; r < 16; r++) {
        int t = wave * 16 + r;
        float z = Ls[lane][t];
        float cnt = 0.f, ss = 0.f;
        #pragma unroll
        for (int j2 = 0; j2 < 64; j2++) {
            float zj = __shfl(z, j2, 64);
            if (zj >= z) { cnt += 1.f; ss += zj; }
        }
        float cond = (1.f + cnt * z > ss) ? 1.f : 0.f;
        float rho = cond, S = cond * z;
        #pragma unroll
        for (int off = 32; off; off >>= 1) {
            rho += __shfl_xor(rho, off, 64);
            S   += __shfl_xor(S,   off, 64);
        }
        float tau = (S - 1.f) / rho;
        Ls[lane][t] = fmaxf(z - tau, 0.f);
    }
    __syncthreads();

    #pragma unroll
    for (int u = 0; u < 4; u++) {
        int d = u * 16 + g;
        float4 v;
        v.x = Ls[d][c * 4 + 0]; v.y = Ls[d][c * 4 + 1];
        v.z = Ls[d][c * 4 + 2]; v.w = Ls[d][c * 4 + 3];
        *(float4*)&base[(size_t)d * TT + c * 4] = v;
    }
}

// ---------------------------------------------------------------------------
// Tiled flash attention + XSA correction (fp32 compute; V stored fp16).
// 512 blocks x 4 q-tiles {p, 31-p, p+8, 23-p} -> uniform work. K/V register
// prefetch hides global latency behind previous tile's compute.
// Output written as fp16 split Yh/Yl for the MFMA out-projection.
// ---------------------------------------------------------------------------
__global__ __launch_bounds__(256, 3) void attn_kernel(
    const float* __restrict__ Qtg, const float* __restrict__ Ktg,
    const _Float16* __restrict__ V, _Float16* __restrict__ Yh,
    _Float16* __restrict__ Yl)
{
    __shared__ float Qs[64][68];    // [d][q]
    __shared__ float KPs[64][72];   // K tile [d][k] (^d&3) / P [q][k] (^(q>>2)&3)
    __shared__ float Vs[64][72];    // [k][d] (^k&3)

    const int blk = blockIdx.x;
    const int bhid = blk >> 3;
    const int p = blk & 7;
    const int b = bhid >> 4, h = bhid & 15;
    const size_t bh = (size_t)b * NH + h;
    const float* Qg = Qtg + bh * DD * TT;       // [d][t]
    const float* Kg = Ktg + bh * DD * TT;       // [d][t]
    const _Float16* Vg = V + bh * TT * DD;      // [t][d] fp16

    const int tid = threadIdx.x;
    const int g = tid >> 4, c = tid & 15;
    const int tm = g * 4, tn = c * 4;

    const int qlist[4] = {p, 31 - p, p + 8, 23 - p};

    for (int qi = 0; qi < 4; qi++) {
        const int qt = qlist[qi];
        __syncthreads();

        // stage Q tile: Qs[d][q] (already scaled by 0.125)
        #pragma unroll
        for (int u = 0; u < 4; u++) {
            int d = u * 16 + g;
            float4 v = *(const float4*)&Qg[(size_t)d * TT + qt * 64 + tn];
            Qs[d][tn + 0] = v.x; Qs[d][tn + 1] = v.y;
            Qs[d][tn + 2] = v.z; Qs[d][tn + 3] = v.w;
        }

        float4 kpre[4];
        half4 vpre[4];
        #pragma unroll
        for (int u = 0; u < 4; u++) {
            int d = u * 16 + g;
            kpre[u] = *(const float4*)&Kg[(size_t)d * TT + tn];
            vpre[u] = *(const half4*)&Vg[(size_t)(u * 16 + g) * DD + tn];
        }

        float acc[4][4] = {};
        float m_i[4], l_i[4];
        #pragma unroll
        for (int i = 0; i < 4; i++) { m_i[i] = -3.0e38f; l_i[i] = 0.f; }

        for (int kt = 0; kt <= qt; kt++) {
            __syncthreads();
            #pragma unroll
            for (int u = 0; u < 4; u++) {
                int d = u * 16 + g;
                *(float4*)&KPs[d][4 * (c ^ (d & 3))] = kpre[u];
                float4 vv;
                vv.x = (float)vpre[u].x; vv.y = (float)vpre[u].y;
                vv.z = (float)vpre[u].z; vv.w = (float)vpre[u].w;
                *(float4*)&Vs[d][4 * (c ^ (d & 3))] = vv;
            }
            if (kt < qt) {
                const int kn = (kt + 1) * 64;
                #pragma unroll
                for (int u = 0; u < 4; u++) {
                    int d = u * 16 + g;
                    kpre[u] = *(const float4*)&Kg[(size_t)d * TT + kn + tn];
                    vpre[u] = *(const half4*)&Vg[(size_t)(kn + u * 16 + g) * DD + tn];
                }
            }
            __syncthreads();

            float s[4][4] = {};
            #pragma unroll 8
            for (int d = 0; d < 64; d++) {
                float4 qv = *(const float4*)&Qs[d][tm];
                float4 kv = *(const float4*)&KPs[d][4 * (c ^ (d & 3))];
                float a[4] = {qv.x, qv.y, qv.z, qv.w};
                float bb[4] = {kv.x, kv.y, kv.z, kv.w};
                #pragma unroll
                for (int i = 0; i < 4; i++)
                    #pragma unroll
                    for (int j = 0; j < 4; j++)
                        s[i][j] = fmaf(a[i], bb[j], s[i][j]);
            }

            if (kt == qt) {
                #pragma unroll
                for (int i = 0; i < 4; i++)
                    #pragma unroll
                    for (int j = 0; j < 4; j++)
                        if (tn + j > tm + i) s[i][j] = -1.0e30f;
            }

            float alpha[4];
            #pragma unroll
            for (int i = 0; i < 4; i++) {
                float rmax = fmaxf(fmaxf(s[i][0], s[i][1]), fmaxf(s[i][2], s[i][3]));
                #pragma unroll
                for (int off = 8; off; off >>= 1)
                    rmax = fmaxf(rmax, __shfl_xor(rmax, off, 64));
                float mnew = fmaxf(m_i[i], rmax);
                alpha[i] = __expf(m_i[i] - mnew);
                float rs = 0.f;
                #pragma unroll
                for (int j = 0; j < 4; j++) {
                    float pp = __expf(s[i][j] - mnew);
                    s[i][j] = pp;
                    rs += pp;
                }
                #pragma unroll
                for (int off = 8; off; off >>= 1)
                    rs += __shfl_xor(rs, off, 64);
                l_i[i] = l_i[i] * alpha[i] + rs;
                m_i[i] = mnew;
            }
            #pragma unroll
            for (int i = 0; i < 4; i++)
                #pragma unroll
                for (int j = 0; j < 4; j++)
                    acc[i][j] *= alpha[i];

            __syncthreads();
            #pragma unroll
            for (int i = 0; i < 4; i++) {
                float4 pv = {s[i][0], s[i][1], s[i][2], s[i][3]};
                *(float4*)&KPs[tm + i][4 * (c ^ (g & 3))] = pv;
            }
            __syncthreads();

            #pragma unroll 4
            for (int k0 = 0; k0 < 64; k0 += 4) {
                float4 pv[4], vv[4];
                #pragma unroll
                for (int i = 0; i < 4; i++)
                    pv[i] = *(const float4*)&KPs[tm + i][4 * ((k0 >> 2) ^ (g & 3))];
                #pragma unroll
                for (int kk = 0; kk < 4; kk++)
                    vv[kk] = *(const float4*)&Vs[k0 + kk][4 * (c ^ ((k0 + kk) & 3))];
                #pragma unroll
                for (int i = 0; i < 4; i++) {
                    float pr[4] = {pv[i].x, pv[i].y, pv[i].z, pv[i].w};
                    #pragma unroll
                    for (int kk = 0; kk < 4; kk++) {
                        float vr[4] = {vv[kk].x, vv[kk].y, vv[kk].z, vv[kk].w};
                        #pragma unroll
                        for (int j = 0; j < 4; j++)
                            acc[i][j] = fmaf(pr[kk], vr[j], acc[i][j]);
                    }
                }
            }
        }

        // epilogue: normalize, XSA correction, store Yh/Yl (fp16 split)
        #pragma unroll
        for (int i = 0; i < 4; i++) {
            const int q = qt * 64 + tm + i;
            const float inv_l = 1.0f / l_i[i];
            float y[4];
            #pragma unroll
            for (int j = 0; j < 4; j++) y[j] = acc[i][j] * inv_l;

            half4 vq4 = *(const half4*)&Vg[(size_t)q * DD + tn];
            float vq[4] = {(float)vq4.x, (float)vq4.y, (float)vq4.z, (float)vq4.w};
            float n2 = vq[0]*vq[0] + vq[1]*vq[1] + vq[2]*vq[2] + vq[3]*vq[3];
            #pragma unroll
            for (int off = 8; off; off >>= 1) n2 += __shfl_xor(n2, off, 64);
            float inv_vn = 1.0f / fmaxf(sqrtf(n2), 1e-12f);

            float coef = 0.f;
            #pragma unroll
            for (int j = 0; j < 4; j++) coef += y[j] * (vq[j] * inv_vn);
            #pragma unroll
            for (int off = 8; off; off >>= 1) coef += __shfl_xor(coef, off, 64);

            float o[4];
            #pragma unroll
            for (int j = 0; j < 4; j++) o[j] = y[j] - coef * vq[j] * inv_vn;

            half4 hv, lv;
            hv.x = (_Float16)o[0]; lv.x = (_Float16)(o[0] - (float)hv.x);
            hv.y = (_Float16)o[1]; lv.y = (_Float16)(o[1] - (float)hv.y);
            hv.z = (_Float16)o[2]; lv.z = (_Float16)(o[2] - (float)hv.z);
            hv.w = (_Float16)o[3]; lv.w = (_Float16)(o[3] - (float)hv.w);
            const size_t off2 = ((size_t)(b * TT + q)) * CC + h * DD + tn;
            *(half4*)&Yh[off2] = hv;
            *(half4*)&Yl[off2] = lv;
        }
    }
}

// ---------------------------------------------------------------------------
extern "C" void kernel_launch(void* const* d_in, const int* in_sizes, int n_in,
                              void* d_out, int out_size, void* d_ws, size_t ws_size,
                              hipStream_t stream) {
    const float* x      = (const float*)d_in[0];
    const float* W_attn = (const float*)d_in[1];
    const float* b_attn = (const float*)d_in[2];
    const float* W_proj = (const float*)d_in[3];
    const float* b_proj = (const float*)d_in[4];
    float* out = (float*)d_out;

    // workspace layout (124 MiB):
    // [0,16)    MiB: xh fp16 (dead after gemm1; reused as Yh)
    // [16,32)   MiB: xl fp16 (dead after gemm1; reused as Yl)
    // [32,38)   MiB: WhT fp16 (dead after gemm1; [32,34) reused for W_proj hi)
    // [38,44)   MiB: WlT fp16 ([34,36) reused for W_proj lo)
    // [44,76)   MiB: Q fp32 [b,h,d,t], pre-scaled
    // [76,108)  MiB: K fp32 [b,h,d,t]
    // [108,124) MiB: V fp16 [b,h,t,d]
    char* ws = (char*)d_ws;
    _Float16* xh   = (_Float16*)(ws);
    _Float16* xl   = (_Float16*)(ws + ((size_t)16 << 20));
    _Float16* WhT  = (_Float16*)(ws + ((size_t)32 << 20));
    _Float16* WlT  = (_Float16*)(ws + ((size_t)38 << 20));
    float*    Qtg  = (float*)(ws + ((size_t)44 << 20));
    float*    Ktg  = (float*)(ws + ((size_t)76 << 20));
    _Float16* Vh   = (_Float16*)(ws + ((size_t)108 << 20));
    _Float16* Yh   = xh;
    _Float16* Yl   = xl;
    _Float16* WphT = WhT;
    _Float16* WplT = (_Float16*)(ws + ((size_t)34 << 20));

    // 1) split x -> fp16 hi/lo
    split_x_kernel<<<(MM * CC) / (256 * 4), 256, 0, stream>>>(x, xh, xl);
    // 2) transpose+split W_attn -> [3C, C] fp16 hi/lo
    splitT_w_kernel<<<dim3(3 * CC / 64, CC / 64), 256, 0, stream>>>(
        W_attn, WhT, WlT, CC, 3 * CC);
    // 3) QKV GEMM (split-fp16 MFMA) with scatter
    gemm_ht3_kernel<<<dim3(3 * CC / 128, MM / 128), 256, 0, stream>>>(
        xh, xl, WhT, WlT, b_attn, nullptr, Qtg, Ktg, Vh, 3 * CC, CC, 1);
    // 4) sparsemax over D of K
    sparsemax_t_kernel<<<dim3(TT / 64, NB * NH), 256, 0, stream>>>(Ktg);
    // 5) fused attention; writes Yh/Yl fp16 split
    attn_kernel<<<dim3(512), 256, 0, stream>>>(Qtg, Ktg, Vh, Yh, Yl);
    // 6) transpose+split W_proj
    splitT_w_kernel<<<dim3(CC / 64, CC / 64), 256, 0, stream>>>(
        W_proj, WphT, WplT, CC, CC);
    // 7) output projection (split-fp16 MFMA)
    gemm_ht3_kernel<<<dim3(CC / 128, MM / 128), 256, 0, stream>>>(
        Yh, Yl, WphT, WplT, b_proj, out, nullptr, nullptr, nullptr, CC, CC, 0);
}